// Round 1
// baseline (410.788 us; speedup 1.0000x reference)
//
#include <hip/hip_runtime.h>

#define T_LEN 3000
#define TQ 750      // T/4 float4 chunks
#define C_CH 8
#define NTHREADS 256
#define NWAVES 4

// 4 waves (256 threads) per (b,f) slice; threads stride over T in float4 steps.
// Single pass: accumulate UNNORMALIZED mask-weighted outer products + mask sum,
// divide once in the epilogue (normalization is linear in the mask).
// Per-lane 64 accumulators: [0..7] diag re, [8..35] offdiag re, [36..63] offdiag im.
// Pair index p = 7c - c(c-1)/2 + (e-c-1) for c<e.
// Epilogue: per-wave butterfly transpose-reduce (63 shfl) -> lane k holds wave
// partial of output k; tiny LDS combine across the 4 waves; Hermitian scatter.
// Output: REAL plane (B,F,C,C) float32, then planar imag if out_size permits.

#define XPOSE_ROUND(OFF)                                        \
    {                                                           \
        const bool hi = (lane & (OFF)) != 0;                    \
        _Pragma("unroll")                                       \
        for (int i = 0; i < (OFF); ++i) {                       \
            float send = hi ? acc[i] : acc[i + (OFF)];          \
            float recv = __shfl_xor(send, (OFF));               \
            float keep = hi ? acc[i + (OFF)] : acc[i];          \
            acc[i] = keep + recv;                               \
        }                                                       \
    }

__global__ __launch_bounds__(NTHREADS) void psd_kernel(
        const float* __restrict__ Xr,
        const float* __restrict__ Xi,
        const float* __restrict__ Mk,
        float* __restrict__ out,
        int real_elems, int write_imag) {
    const int slice = blockIdx.x;
    const int tid   = threadIdx.x;
    const int lane  = tid & 63;
    const int wave  = tid >> 6;

    const float4* xr4 = reinterpret_cast<const float4*>(Xr) + (size_t)slice * (C_CH * TQ);
    const float4* xi4 = reinterpret_cast<const float4*>(Xi) + (size_t)slice * (C_CH * TQ);
    const float4* mk4 = reinterpret_cast<const float4*>(Mk) + (size_t)slice * TQ;

    float acc[64];
#pragma unroll
    for (int k = 0; k < 64; ++k) acc[k] = 0.f;
    float s = 0.f;   // raw mask sum (normalization deferred to epilogue)

    for (int q = tid; q < TQ; q += NTHREADS) {
        float4 mv = mk4[q];
        s += (mv.x + mv.y) + (mv.z + mv.w);
        float ar[C_CH][4], ai[C_CH][4];
#pragma unroll
        for (int c = 0; c < C_CH; ++c) {
            float4 v = xr4[c * TQ + q];
            ar[c][0] = v.x; ar[c][1] = v.y; ar[c][2] = v.z; ar[c][3] = v.w;
            float4 w = xi4[c * TQ + q];
            ai[c][0] = w.x; ai[c][1] = w.y; ai[c][2] = w.z; ai[c][3] = w.w;
        }
        const float mm[4] = {mv.x, mv.y, mv.z, mv.w};
#pragma unroll
        for (int j = 0; j < 4; ++j) {
            const float m = mm[j];
            float mr[C_CH], mi[C_CH];
#pragma unroll
            for (int c = 0; c < C_CH; ++c) {
                mr[c] = m * ar[c][j];
                mi[c] = m * ai[c][j];
            }
            // diagonal: re = m*(xr^2 + xi^2)
#pragma unroll
            for (int c = 0; c < C_CH; ++c)
                acc[c] += mr[c] * ar[c][j] + mi[c] * ai[c][j];
            // upper triangle: psd[c][e] = sum m * X[c] * conj(X[e])
#pragma unroll
            for (int c = 0; c < C_CH; ++c) {
#pragma unroll
                for (int e = c + 1; e < C_CH; ++e) {
                    const int p = 7 * c - (c * (c - 1)) / 2 + (e - c - 1);
                    acc[8 + p]  += mr[c] * ar[e][j] + mi[c] * ai[e][j];
                    acc[36 + p] += mi[c] * ar[e][j] - mr[c] * ai[e][j];
                }
            }
        }
    }

    // ---- per-wave mask-sum reduce (butterfly) ----
#pragma unroll
    for (int off = 32; off > 0; off >>= 1) s += __shfl_xor(s, off);

    // ---- per-wave transpose-reduce: lane k ends with wave-partial of acc k ----
    XPOSE_ROUND(32)
    XPOSE_ROUND(16)
    XPOSE_ROUND(8)
    XPOSE_ROUND(4)
    XPOSE_ROUND(2)
    XPOSE_ROUND(1)
    // acc[0] now = sum over this wave's lanes of accumulator index 'lane'

    // ---- cross-wave combine in (tiny) LDS ----
    __shared__ float red[NWAVES * 64];
    __shared__ float sred[NWAVES];
    __shared__ float fin[128];   // [0..63] real plane (c*8+e), [64..127] imag plane
    red[wave * 64 + lane] = acc[0];
    if (lane == 0) sred[wave] = s;
    __syncthreads();

    if (tid < 64) {
        float tot = (red[tid] + red[64 + tid]) + (red[128 + tid] + red[192 + tid]);
        const float stot = (sred[0] + sred[1]) + (sred[2] + sred[3]);
        tot *= 1.0f / (stot + 1e-15f);

        // scatter into per-slice real/imag planes via Hermitian symmetry
        if (tid < 8) {
            const int c = tid;
            fin[c * 8 + c]      = tot;   // diag re
            fin[64 + c * 8 + c] = 0.f;   // diag im = 0 exactly
        } else {
            int p = (tid < 36) ? (tid - 8) : (tid - 36);
            int c = 0;
            while (p >= 7 - c) { p -= 7 - c; ++c; }
            const int e = c + 1 + p;
            if (tid < 36) {        // real part, symmetric
                fin[c * 8 + e] = tot;
                fin[e * 8 + c] = tot;
            } else {               // imag part, antisymmetric
                fin[64 + c * 8 + e] = tot;
                fin[64 + e * 8 + c] = -tot;
            }
        }
    }
    __syncthreads();
    if (tid < 64) {
        out[(size_t)slice * 64 + tid] = fin[tid];
    } else if (tid < 128 && write_imag) {
        out[(size_t)real_elems + (size_t)slice * 64 + (tid - 64)] = fin[tid];
    }
}

extern "C" void kernel_launch(void* const* d_in, const int* in_sizes, int n_in,
                              void* d_out, int out_size, void* d_ws, size_t ws_size,
                              hipStream_t stream) {
    const float* Xr = (const float*)d_in[0];
    const float* Xi = (const float*)d_in[1];
    const float* Mk = (const float*)d_in[2];
    float* out = (float*)d_out;
    const int slices = in_sizes[2] / T_LEN;   // B*F = 2056
    const int real_elems = slices * 64;       // B*F*C*C = 131584
    const int write_imag = (out_size >= 2 * real_elems) ? 1 : 0;
    psd_kernel<<<dim3(slices), dim3(NTHREADS), 0, stream>>>(Xr, Xi, Mk, out,
                                                            real_elems, write_imag);
}

// Round 2
// 404.123 us; speedup vs baseline: 1.0165x; 1.0165x over previous
//
#include <hip/hip_runtime.h>

#define T_LEN 3000
#define TQ2 1500    // T/2 float2 chunks
#define C_CH 8
#define NTHREADS 256
#define NWAVES 4

// 4 waves (256 threads) per (b,f) slice; threads stride over T in float2 steps.
// float2 (not float4) X loads: halves live X registers (32 vs 64) so the
// acc[64]+X live set fits in <128 VGPRs without scratch spills, and doubles
// the iteration count (6/thread) for cross-iteration load pipelining.
// Single pass: accumulate UNNORMALIZED mask-weighted outer products + mask sum,
// divide once in the epilogue (normalization is linear in the mask).
// Per-lane 64 accumulators: [0..7] diag re, [8..35] offdiag re, [36..63] offdiag im.
// Pair index p = 7c - c(c-1)/2 + (e-c-1) for c<e.
// Epilogue: per-wave butterfly transpose-reduce (63 shfl) -> lane k holds wave
// partial of output k; tiny LDS combine across the 4 waves; Hermitian scatter.
// Output: REAL plane (B,F,C,C) float32, then planar imag if out_size permits.

#define XPOSE_ROUND(OFF)                                        \
    {                                                           \
        const bool hi = (lane & (OFF)) != 0;                    \
        _Pragma("unroll")                                       \
        for (int i = 0; i < (OFF); ++i) {                       \
            float send = hi ? acc[i] : acc[i + (OFF)];          \
            float recv = __shfl_xor(send, (OFF));               \
            float keep = hi ? acc[i + (OFF)] : acc[i];          \
            acc[i] = keep + recv;                               \
        }                                                       \
    }

__global__ __launch_bounds__(NTHREADS) void psd_kernel(
        const float* __restrict__ Xr,
        const float* __restrict__ Xi,
        const float* __restrict__ Mk,
        float* __restrict__ out,
        int real_elems, int write_imag) {
    const int slice = blockIdx.x;
    const int tid   = threadIdx.x;
    const int lane  = tid & 63;
    const int wave  = tid >> 6;

    const float2* xr2 = reinterpret_cast<const float2*>(Xr) + (size_t)slice * (C_CH * TQ2);
    const float2* xi2 = reinterpret_cast<const float2*>(Xi) + (size_t)slice * (C_CH * TQ2);
    const float2* mk2 = reinterpret_cast<const float2*>(Mk) + (size_t)slice * TQ2;

    float acc[64];
#pragma unroll
    for (int k = 0; k < 64; ++k) acc[k] = 0.f;
    float s = 0.f;   // raw mask sum (normalization deferred to epilogue)

    for (int q = tid; q < TQ2; q += NTHREADS) {
        float2 mv = mk2[q];
        s += mv.x + mv.y;
        float ar[C_CH][2], ai[C_CH][2];
#pragma unroll
        for (int c = 0; c < C_CH; ++c) {
            float2 v = xr2[c * TQ2 + q];
            ar[c][0] = v.x; ar[c][1] = v.y;
            float2 w = xi2[c * TQ2 + q];
            ai[c][0] = w.x; ai[c][1] = w.y;
        }
        const float mm[2] = {mv.x, mv.y};
#pragma unroll
        for (int j = 0; j < 2; ++j) {
            const float m = mm[j];
            float mr[C_CH], mi[C_CH];
#pragma unroll
            for (int c = 0; c < C_CH; ++c) {
                mr[c] = m * ar[c][j];
                mi[c] = m * ai[c][j];
            }
            // diagonal: re = m*(xr^2 + xi^2)
#pragma unroll
            for (int c = 0; c < C_CH; ++c)
                acc[c] += mr[c] * ar[c][j] + mi[c] * ai[c][j];
            // upper triangle: psd[c][e] = sum m * X[c] * conj(X[e])
#pragma unroll
            for (int c = 0; c < C_CH; ++c) {
#pragma unroll
                for (int e = c + 1; e < C_CH; ++e) {
                    const int p = 7 * c - (c * (c - 1)) / 2 + (e - c - 1);
                    acc[8 + p]  += mr[c] * ar[e][j] + mi[c] * ai[e][j];
                    acc[36 + p] += mi[c] * ar[e][j] - mr[c] * ai[e][j];
                }
            }
        }
    }

    // ---- per-wave mask-sum reduce (butterfly) ----
#pragma unroll
    for (int off = 32; off > 0; off >>= 1) s += __shfl_xor(s, off);

    // ---- per-wave transpose-reduce: lane k ends with wave-partial of acc k ----
    XPOSE_ROUND(32)
    XPOSE_ROUND(16)
    XPOSE_ROUND(8)
    XPOSE_ROUND(4)
    XPOSE_ROUND(2)
    XPOSE_ROUND(1)
    // acc[0] now = sum over this wave's lanes of accumulator index 'lane'

    // ---- cross-wave combine in (tiny) LDS ----
    __shared__ float red[NWAVES * 64];
    __shared__ float sred[NWAVES];
    __shared__ float fin[128];   // [0..63] real plane (c*8+e), [64..127] imag plane
    red[wave * 64 + lane] = acc[0];
    if (lane == 0) sred[wave] = s;
    __syncthreads();

    if (tid < 64) {
        float tot = (red[tid] + red[64 + tid]) + (red[128 + tid] + red[192 + tid]);
        const float stot = (sred[0] + sred[1]) + (sred[2] + sred[3]);
        tot *= 1.0f / (stot + 1e-15f);

        // scatter into per-slice real/imag planes via Hermitian symmetry
        if (tid < 8) {
            const int c = tid;
            fin[c * 8 + c]      = tot;   // diag re
            fin[64 + c * 8 + c] = 0.f;   // diag im = 0 exactly
        } else {
            int p = (tid < 36) ? (tid - 8) : (tid - 36);
            int c = 0;
            while (p >= 7 - c) { p -= 7 - c; ++c; }
            const int e = c + 1 + p;
            if (tid < 36) {        // real part, symmetric
                fin[c * 8 + e] = tot;
                fin[e * 8 + c] = tot;
            } else {               // imag part, antisymmetric
                fin[64 + c * 8 + e] = tot;
                fin[64 + e * 8 + c] = -tot;
            }
        }
    }
    __syncthreads();
    if (tid < 64) {
        out[(size_t)slice * 64 + tid] = fin[tid];
    } else if (tid < 128 && write_imag) {
        out[(size_t)real_elems + (size_t)slice * 64 + (tid - 64)] = fin[tid];
    }
}

extern "C" void kernel_launch(void* const* d_in, const int* in_sizes, int n_in,
                              void* d_out, int out_size, void* d_ws, size_t ws_size,
                              hipStream_t stream) {
    const float* Xr = (const float*)d_in[0];
    const float* Xi = (const float*)d_in[1];
    const float* Mk = (const float*)d_in[2];
    float* out = (float*)d_out;
    const int slices = in_sizes[2] / T_LEN;   // B*F = 2056
    const int real_elems = slices * 64;       // B*F*C*C = 131584
    const int write_imag = (out_size >= 2 * real_elems) ? 1 : 0;
    psd_kernel<<<dim3(slices), dim3(NTHREADS), 0, stream>>>(Xr, Xi, Mk, out,
                                                            real_elems, write_imag);
}